// Round 1
// baseline (3162.025 us; speedup 1.0000x reference)
//
#include <hip/hip_runtime.h>
#include <math.h>

// Problem constants (fixed shapes from the reference)
#define BB 32
#define SS 256
#define EE 300
#define EP 304          // E padded to multiple of 16
#define HH 256
#define TT 19           // NUM_TAGS + START + STOP
#define START_TAG 17
#define STOP_TAG 18
#define BS 8192         // B*S
#define GIN_PER_DIR (8192*1024)

__device__ __forceinline__ float sigm(float x){ return 1.0f/(1.0f+expf(-x)); }

// ---------------- ws layout (float offsets) ----------------
// x_pad : [BS][304]            off 0          size 2490368
// WT    : [304][2048]          off 2490368    size 622592   (transposed+padded Wih_f|Wih_b)
// bias2 : [2048]               off 3112960    size 2048     (bih+bhh per gate row, both dirs)
// Wpk   : [2][256k][256j][4g]  off 3115008    size 524288   (Whh packed for float4 loads)
// gin   : [2][BS][1024]        off 3639296    size 16777216 (input-gate preactivations)
// hseq  : [BS][512]            off 20416512   size 4194304  (concat hf|hb)
// emit  : [BS][19]             off 24610816   size 155648
// ptr   : [BS][19] (int)       off 24766464   size 155648
// nll   : [32]                 off 24922112
// total ~ 99.7 MB

// -------- embed gather + mask, pad E to 304 with zeros --------
__global__ void k_embed(const int* __restrict__ wi, const int* __restrict__ msk,
                        const float* __restrict__ emb, float* __restrict__ x){
  int id = blockIdx.x*256 + threadIdx.x;        // BS*76 float4 slots
  if (id >= BS*76) return;
  int row = id / 76, q = id - row*76;
  float4 v = make_float4(0.f,0.f,0.f,0.f);
  if (q < 75){                                   // 75*4 = 300 real elements
    const float4* e4 = (const float4*)emb;       // emb rows are 1200B = 16B aligned
    v = e4[(size_t)wi[row]*75 + q];
    float m = (float)msk[row];
    v.x*=m; v.y*=m; v.z*=m; v.w*=m;
  }
  ((float4*)x)[(size_t)row*76 + q] = v;
}

// -------- transpose Wih (both dirs) into WT[304][2048], build combined bias --------
__global__ void k_prep_wt(const float* __restrict__ Wih_f, const float* __restrict__ Wih_b,
                          const float* __restrict__ bih_f, const float* __restrict__ bhh_f,
                          const float* __restrict__ bih_b, const float* __restrict__ bhh_b,
                          float* __restrict__ WT, float* __restrict__ bias){
  int id = blockIdx.x*256 + threadIdx.x;
  if (id < 304*2048){
    int k = id >> 11, n = id & 2047;
    float v = 0.f;
    if (k < 300) v = (n < 1024) ? Wih_f[n*300 + k] : Wih_b[(n-1024)*300 + k];
    WT[id] = v;
  } else {
    int n = id - 304*2048;
    if (n < 2048)
      bias[n] = (n < 1024) ? (bih_f[n] + bhh_f[n]) : (bih_b[n-1024] + bhh_b[n-1024]);
  }
}

// -------- pack Whh into [k][j][4 gates] per dir for coalesced float4 streaming --------
__global__ void k_prep_whh(const float* __restrict__ Whh_f, const float* __restrict__ Whh_b,
                           float* __restrict__ Wpk){
  int d = blockIdx.y;
  int id = blockIdx.x*256 + threadIdx.x;        // < 262144
  const float* W = d ? Whh_b : Whh_f;
  int g = id & 3, j = (id >> 2) & 255, k = id >> 10;
  Wpk[d*262144 + id] = W[(g*256 + j)*256 + k];
}

// -------- input-gate GEMM: gin[d][row][g*256+j] = x @ Wih^T + (bih+bhh) --------
__global__ __launch_bounds__(256) void k_gemm(const float* __restrict__ x,
      const float* __restrict__ WT, const float* __restrict__ bias,
      float* __restrict__ gin){
  __shared__ float As[16][65];
  __shared__ float Bs[16][64];
  int tid = threadIdx.x;
  int tx = tid & 15, ty = tid >> 4;
  int n0 = blockIdx.x * 64, m0 = blockIdx.y * 64;
  float acc[4][4] = {};
  for (int kt = 0; kt < 19; ++kt){
    int k0 = kt*16;
    #pragma unroll
    for (int i = 0; i < 4; ++i){
      int idx = tid + i*256;
      int ak = idx & 15, am = idx >> 4;
      As[ak][am] = x[(size_t)(m0+am)*304 + (k0+ak)];
      int bn = idx & 63, bk = idx >> 6;
      Bs[bk][bn] = WT[(size_t)(k0+bk)*2048 + (n0+bn)];
    }
    __syncthreads();
    #pragma unroll
    for (int k = 0; k < 16; ++k){
      float a0 = As[k][ty*4+0], a1 = As[k][ty*4+1], a2 = As[k][ty*4+2], a3 = As[k][ty*4+3];
      float b0 = Bs[k][tx*4+0], b1 = Bs[k][tx*4+1], b2 = Bs[k][tx*4+2], b3 = Bs[k][tx*4+3];
      acc[0][0]+=a0*b0; acc[0][1]+=a0*b1; acc[0][2]+=a0*b2; acc[0][3]+=a0*b3;
      acc[1][0]+=a1*b0; acc[1][1]+=a1*b1; acc[1][2]+=a1*b2; acc[1][3]+=a1*b3;
      acc[2][0]+=a2*b0; acc[2][1]+=a2*b1; acc[2][2]+=a2*b2; acc[2][3]+=a2*b3;
      acc[3][0]+=a3*b0; acc[3][1]+=a3*b1; acc[3][2]+=a3*b2; acc[3][3]+=a3*b3;
    }
    __syncthreads();
  }
  #pragma unroll
  for (int i = 0; i < 4; ++i){
    int m = m0 + ty*4 + i;
    #pragma unroll
    for (int j = 0; j < 4; ++j){
      int n = n0 + tx*4 + j;
      int dd = n >> 10, r = n & 1023;
      gin[(size_t)dd*GIN_PER_DIR + (size_t)m*1024 + r] = acc[i][j] + bias[n];
    }
  }
}

// -------- BiLSTM recurrence: one WG per (batch, dir); thread j owns h[j], c[j] --------
__global__ __launch_bounds__(256) void k_lstm(const float* __restrict__ gin,
                 const float* __restrict__ Wpk, float* __restrict__ hseq){
  int tid = threadIdx.x;
  int b = blockIdx.x & 31, d = blockIdx.x >> 5;
  const float* gb = gin + (size_t)d*GIN_PER_DIR + (size_t)b*SS*1024;
  const float4* wb = ((const float4*)(Wpk + (size_t)d*262144)) + tid;  // [k*256 + j]
  __shared__ float hs[256];
  float c = 0.f;
  hs[tid] = 0.f;
  __syncthreads();
  for (int s = 0; s < SS; ++s){
    int t = d ? (SS-1-s) : s;
    const float* gr = gb + t*1024 + tid;
    float4 acc;
    acc.x = gr[0]; acc.y = gr[256]; acc.z = gr[512]; acc.w = gr[768];
    #pragma unroll 4
    for (int k = 0; k < 256; k += 4){
      float4 h4 = *(const float4*)&hs[k];
      float4 w0 = wb[(k+0)*256];
      float4 w1 = wb[(k+1)*256];
      float4 w2 = wb[(k+2)*256];
      float4 w3 = wb[(k+3)*256];
      acc.x += w0.x*h4.x + w1.x*h4.y + w2.x*h4.z + w3.x*h4.w;
      acc.y += w0.y*h4.x + w1.y*h4.y + w2.y*h4.z + w3.y*h4.w;
      acc.z += w0.z*h4.x + w1.z*h4.y + w2.z*h4.z + w3.z*h4.w;
      acc.w += w0.w*h4.x + w1.w*h4.y + w2.w*h4.z + w3.w*h4.w;
    }
    float iv = sigm(acc.x), fv = sigm(acc.y), gv = tanhf(acc.z), ov = sigm(acc.w);
    c = fv*c + iv*gv;
    float hv = ov*tanhf(c);
    hseq[((size_t)(b*SS + t))*512 + d*256 + tid] = hv;
    __syncthreads();
    hs[tid] = hv;
    __syncthreads();
  }
}

// -------- tag logits: emit[row][t] = hseq[row] . W_tag[t] + b_tag[t] --------
__global__ void k_emit(const float* __restrict__ hseq, const float* __restrict__ Wtag,
                       const float* __restrict__ btag, float* __restrict__ emit){
  int id = blockIdx.x*256 + threadIdx.x;
  if (id >= BS*TT) return;
  int row = id / TT, tg = id - row*TT;
  const float4* hp = (const float4*)(hseq + (size_t)row*512);
  const float4* wp = (const float4*)(Wtag + (size_t)tg*512);
  float acc = btag[tg];
  #pragma unroll 8
  for (int k = 0; k < 128; ++k){
    float4 h = hp[k], w = wp[k];
    acc += h.x*w.x + h.y*w.y + h.z*w.z + h.w*w.w;
  }
  emit[id] = acc;
}

// -------- CRF NLL (forward algorithm + gold score), one wave per batch --------
__global__ void k_crf(const float* __restrict__ emit, const int* __restrict__ msk,
                      const int* __restrict__ lab, const float* __restrict__ trans,
                      float* __restrict__ nll){
  int b = blockIdx.x, tid = threadIdx.x;
  __shared__ float tr[361];
  __shared__ float al[19];
  for (int i = tid; i < 361; i += 64) tr[i] = trans[i];
  const float* eb = emit + (size_t)b*SS*TT;
  const int* mb = msk + b*SS;
  const int* lb = lab + b*SS;
  __syncthreads();
  // gold path score + length (parallel over t, wave reduce)
  float gp = 0.f; int ln = 0;
  for (int t = tid; t < SS; t += 64){
    int m = mb[t];
    ln += m;
    if (m){
      int l = lb[t];
      int p = t ? lb[t-1] : START_TAG;
      gp += tr[p*19 + l] + eb[t*19 + l];
    }
  }
  for (int off = 32; off; off >>= 1){ gp += __shfl_down(gp, off); ln += __shfl_down(ln, off); }
  float gold = 0.f;
  if (tid == 0){
    int lt = lb[ln - 1];
    gold = gp + tr[lt*19 + STOP_TAG];
  }
  if (tid < 19) al[tid] = eb[tid] + tr[START_TAG*19 + tid];
  __syncthreads();
  for (int t = 1; t < SS; ++t){
    int m = mb[t];
    float nv = 0.f;
    if (tid < 19){
      float mx = -1e30f;
      for (int p = 0; p < 19; ++p){ float v = al[p] + tr[p*19 + tid]; mx = fmaxf(mx, v); }
      float sum = 0.f;
      for (int p = 0; p < 19; ++p) sum += expf(al[p] + tr[p*19 + tid] - mx);
      nv = mx + logf(sum) + eb[t*19 + tid];
    }
    __syncthreads();
    if (tid < 19 && m) al[tid] = nv;
    __syncthreads();
  }
  if (tid == 0){
    float mx = -1e30f;
    for (int c2 = 0; c2 < 19; ++c2) mx = fmaxf(mx, al[c2] + tr[c2*19 + STOP_TAG]);
    float sum = 0.f;
    for (int c2 = 0; c2 < 19; ++c2) sum += expf(al[c2] + tr[c2*19 + STOP_TAG] - mx);
    nll[b] = (mx + logf(sum)) - gold;
  }
}

// -------- Viterbi decode, one wave per batch; writes tags (as float) to d_out[1..] --------
__global__ void k_vit(const float* __restrict__ emit, const int* __restrict__ msk,
                      const float* __restrict__ trans, int* __restrict__ ptr,
                      float* __restrict__ out){
  int b = blockIdx.x, tid = threadIdx.x;
  __shared__ float tr[361];
  __shared__ float dl[19];
  __shared__ int tg[256];
  for (int i = tid; i < 361; i += 64) tr[i] = trans[i];
  const float* eb = emit + (size_t)b*SS*TT;
  const int* mb = msk + b*SS;
  int* pb = ptr + (size_t)b*SS*TT;
  if (tid < 19) dl[tid] = eb[tid] + tr[START_TAG*19 + tid];
  __syncthreads();
  for (int t = 1; t < SS; ++t){
    int m = mb[t];
    float best = -1e30f; int bp = 0;
    if (tid < 19){
      for (int p = 0; p < 19; ++p){
        float v = dl[p] + tr[p*19 + tid];
        if (v > best){ best = v; bp = p; }       // strict > == first-max (jnp.argmax)
      }
    }
    __syncthreads();
    if (tid < 19){
      if (m){ dl[tid] = best + eb[t*19 + tid]; pb[t*19 + tid] = bp; }
      else  { pb[t*19 + tid] = tid; }            // identity pass-through when padded
    }
    __syncthreads();
  }
  if (tid == 0){
    float bv = -1e30f; int bl = 0;
    for (int c2 = 0; c2 < 19; ++c2){
      float v = dl[c2] + tr[c2*19 + STOP_TAG];
      if (v > bv){ bv = v; bl = c2; }
    }
    tg[SS-1] = bl;
    for (int t = SS-1; t > 0; --t) tg[t-1] = pb[t*19 + tg[t]];
  }
  __syncthreads();
  for (int t = tid; t < SS; t += 64)
    out[1 + b*SS + t] = (float)(tg[t] * mb[t]);
}

// -------- final loss reduce: d_out[0] = sum(nll)/B --------
__global__ void k_final(const float* __restrict__ nll, float* __restrict__ out){
  int tid = threadIdx.x;
  float v = (tid < 32) ? nll[tid] : 0.f;
  for (int off = 32; off; off >>= 1) v += __shfl_down(v, off);
  if (tid == 0) out[0] = v * (1.0f/32.0f);
}

extern "C" void kernel_launch(void* const* d_in, const int* in_sizes, int n_in,
                              void* d_out, int out_size, void* d_ws, size_t ws_size,
                              hipStream_t stream){
  const int*   wi    = (const int*)d_in[0];
  const int*   msk   = (const int*)d_in[1];
  const int*   lab   = (const int*)d_in[2];
  // d_in[3] labels_token, d_in[4] data_type: unused (data_type==1 branch)
  const float* emb   = (const float*)d_in[5];
  const float* Wih_f = (const float*)d_in[6];
  const float* Whh_f = (const float*)d_in[7];
  const float* bih_f = (const float*)d_in[8];
  const float* bhh_f = (const float*)d_in[9];
  const float* Wih_b = (const float*)d_in[10];
  const float* Whh_b = (const float*)d_in[11];
  const float* bih_b = (const float*)d_in[12];
  const float* bhh_b = (const float*)d_in[13];
  const float* Wtag  = (const float*)d_in[14];
  const float* btag  = (const float*)d_in[15];
  const float* trans = (const float*)d_in[16];

  float* ws   = (float*)d_ws;
  float* x    = ws;
  float* WT   = ws + 2490368;
  float* bias = ws + 3112960;
  float* Wpk  = ws + 3115008;
  float* gin  = ws + 3639296;
  float* hseq = ws + 20416512;
  float* emit = ws + 24610816;
  int*   ptr  = (int*)(ws + 24766464);
  float* nll  = ws + 24922112;
  float* out  = (float*)d_out;

  hipLaunchKernelGGL(k_embed,    dim3(2432),    dim3(256), 0, stream, wi, msk, emb, x);
  hipLaunchKernelGGL(k_prep_wt,  dim3(2440),    dim3(256), 0, stream,
                     Wih_f, Wih_b, bih_f, bhh_f, bih_b, bhh_b, WT, bias);
  hipLaunchKernelGGL(k_prep_whh, dim3(1024,2),  dim3(256), 0, stream, Whh_f, Whh_b, Wpk);
  hipLaunchKernelGGL(k_gemm,     dim3(32,128),  dim3(256), 0, stream, x, WT, bias, gin);
  hipLaunchKernelGGL(k_lstm,     dim3(64),      dim3(256), 0, stream, gin, Wpk, hseq);
  hipLaunchKernelGGL(k_emit,     dim3(608),     dim3(256), 0, stream, hseq, Wtag, btag, emit);
  hipLaunchKernelGGL(k_crf,      dim3(32),      dim3(64),  0, stream, emit, msk, lab, trans, nll);
  hipLaunchKernelGGL(k_vit,      dim3(32),      dim3(64),  0, stream, emit, msk, trans, ptr, out);
  hipLaunchKernelGGL(k_final,    dim3(1),       dim3(64),  0, stream, nll, out);
}

// Round 2
// 2909.066 us; speedup vs baseline: 1.0870x; 1.0870x over previous
//
#include <hip/hip_runtime.h>
#include <math.h>

// Problem constants (fixed shapes from the reference)
#define BB 32
#define SS 256
#define EE 300
#define EP 304          // E padded to multiple of 16
#define HH 256
#define TT 19           // NUM_TAGS + START + STOP
#define START_TAG 17
#define STOP_TAG 18
#define BS 8192         // B*S
#define GIN_PER_DIR (8192*1024)

__device__ __forceinline__ float sigm(float x){ return 1.0f/(1.0f+expf(-x)); }

// ---------------- ws layout (float offsets) ----------------
// x_pad : [BS][304]            off 0          size 2490368
// WT    : [304][2048]          off 2490368    size 622592   (transposed+padded Wih_f|Wih_b)
// bias2 : [2048]               off 3112960    size 2048     (bih+bhh per gate row, both dirs)
// Wp    : [2][64 k4][1024 r]f4 off 3115008    size 524288   (Whh packed: float4 over k, lane-coalesced over r)
// gin   : [2][BS][1024]        off 3639296    size 16777216 (input-gate preactivations)
// hseq  : [BS][512]            off 20416512   size 4194304  (concat hf|hb)
// emit  : [BS][19]             off 24610816   size 155648
// ptr   : [BS][19] (int)       off 24766464   size 155648
// nll   : [32]                 off 24922112

// -------- embed gather + mask, pad E to 304 with zeros --------
__global__ void k_embed(const int* __restrict__ wi, const int* __restrict__ msk,
                        const float* __restrict__ emb, float* __restrict__ x){
  int id = blockIdx.x*256 + threadIdx.x;        // BS*76 float4 slots
  if (id >= BS*76) return;
  int row = id / 76, q = id - row*76;
  float4 v = make_float4(0.f,0.f,0.f,0.f);
  if (q < 75){                                   // 75*4 = 300 real elements
    const float4* e4 = (const float4*)emb;       // emb rows are 1200B = 16B aligned
    v = e4[(size_t)wi[row]*75 + q];
    float m = (float)msk[row];
    v.x*=m; v.y*=m; v.z*=m; v.w*=m;
  }
  ((float4*)x)[(size_t)row*76 + q] = v;
}

// -------- transpose Wih (both dirs) into WT[304][2048], build combined bias --------
__global__ void k_prep_wt(const float* __restrict__ Wih_f, const float* __restrict__ Wih_b,
                          const float* __restrict__ bih_f, const float* __restrict__ bhh_f,
                          const float* __restrict__ bih_b, const float* __restrict__ bhh_b,
                          float* __restrict__ WT, float* __restrict__ bias){
  int id = blockIdx.x*256 + threadIdx.x;
  if (id < 304*2048){
    int k = id >> 11, n = id & 2047;
    float v = 0.f;
    if (k < 300) v = (n < 1024) ? Wih_f[n*300 + k] : Wih_b[(n-1024)*300 + k];
    WT[id] = v;
  } else {
    int n = id - 304*2048;
    if (n < 2048)
      bias[n] = (n < 1024) ? (bih_f[n] + bhh_f[n]) : (bih_b[n-1024] + bhh_b[n-1024]);
  }
}

// -------- pack Whh: Wp[d][k4][r] = float4(Whh_d[r][4k4 .. 4k4+3]) --------
// lane r reads Wp + k4*1024 + r -> consecutive lanes consecutive float4 = coalesced
__global__ void k_prep_whh(const float* __restrict__ Whh_f, const float* __restrict__ Whh_b,
                           float4* __restrict__ Wp){
  int d = blockIdx.y;
  int id = blockIdx.x*256 + threadIdx.x;        // < 65536 per dir
  const float4* W = (const float4*)(d ? Whh_b : Whh_f);   // [1024 rows][64 float4]
  int r = id & 1023, k4 = id >> 10;
  Wp[d*65536 + id] = W[r*64 + k4];
}

// -------- input-gate GEMM: gin[d][row][g*256+j] = x @ Wih^T + (bih+bhh) --------
__global__ __launch_bounds__(256) void k_gemm(const float* __restrict__ x,
      const float* __restrict__ WT, const float* __restrict__ bias,
      float* __restrict__ gin){
  __shared__ float As[16][65];
  __shared__ float Bs[16][64];
  int tid = threadIdx.x;
  int tx = tid & 15, ty = tid >> 4;
  int n0 = blockIdx.x * 64, m0 = blockIdx.y * 64;
  float acc[4][4] = {};
  for (int kt = 0; kt < 19; ++kt){
    int k0 = kt*16;
    #pragma unroll
    for (int i = 0; i < 4; ++i){
      int idx = tid + i*256;
      int ak = idx & 15, am = idx >> 4;
      As[ak][am] = x[(size_t)(m0+am)*304 + (k0+ak)];
      int bn = idx & 63, bk = idx >> 6;
      Bs[bk][bn] = WT[(size_t)(k0+bk)*2048 + (n0+bn)];
    }
    __syncthreads();
    #pragma unroll
    for (int k = 0; k < 16; ++k){
      float a0 = As[k][ty*4+0], a1 = As[k][ty*4+1], a2 = As[k][ty*4+2], a3 = As[k][ty*4+3];
      float b0 = Bs[k][tx*4+0], b1 = Bs[k][tx*4+1], b2 = Bs[k][tx*4+2], b3 = Bs[k][tx*4+3];
      acc[0][0]+=a0*b0; acc[0][1]+=a0*b1; acc[0][2]+=a0*b2; acc[0][3]+=a0*b3;
      acc[1][0]+=a1*b0; acc[1][1]+=a1*b1; acc[1][2]+=a1*b2; acc[1][3]+=a1*b3;
      acc[2][0]+=a2*b0; acc[2][1]+=a2*b1; acc[2][2]+=a2*b2; acc[2][3]+=a2*b3;
      acc[3][0]+=a3*b0; acc[3][1]+=a3*b1; acc[3][2]+=a3*b2; acc[3][3]+=a3*b3;
    }
    __syncthreads();
  }
  #pragma unroll
  for (int i = 0; i < 4; ++i){
    int m = m0 + ty*4 + i;
    #pragma unroll
    for (int j = 0; j < 4; ++j){
      int n = n0 + tx*4 + j;
      int dd = n >> 10, r = n & 1023;
      gin[(size_t)dd*GIN_PER_DIR + (size_t)m*1024 + r] = acc[i][j] + bias[n];
    }
  }
}

// -------- BiLSTM recurrence v2: one WG of 1024 per (batch, dir) --------
// Thread r owns gate-row r (r = g*256 + j). Weights streamed coalesced from L2,
// h broadcast from LDS. 16 waves/CU for latency hiding (needs VGPR <= 128).
__global__ __launch_bounds__(1024) void k_lstm(const float* __restrict__ gin,
                 const float4* __restrict__ Wp, float* __restrict__ hseq){
  int tid = threadIdx.x;
  int b = blockIdx.x & 31, d = blockIdx.x >> 5;
  const float* gb = gin + (size_t)d*GIN_PER_DIR + (size_t)b*SS*1024;
  const float4* wp = Wp + (size_t)d*65536 + tid;   // + k4*1024 per iter
  __shared__ float hs[256];
  __shared__ float gl[1024];
  float c = 0.f;
  if (tid < 256) hs[tid] = 0.f;
  __syncthreads();
  const float4* hs4 = (const float4*)hs;
  for (int s = 0; s < SS; ++s){
    int t = d ? (SS-1-s) : s;
    float acc = gb[(size_t)t*1024 + tid];
    #pragma unroll 8
    for (int k4 = 0; k4 < 64; ++k4){
      float4 w  = wp[k4*1024];
      float4 h4 = hs4[k4];                         // wave-uniform broadcast
      acc += w.x*h4.x + w.y*h4.y + w.z*h4.z + w.w*h4.w;
    }
    gl[tid] = acc;
    __syncthreads();
    if (tid < 256){
      float iv = sigm(gl[tid]),     fv = sigm(gl[tid+256]);
      float gv = tanhf(gl[tid+512]), ov = sigm(gl[tid+768]);
      c = fv*c + iv*gv;
      float hv = ov*tanhf(c);
      hs[tid] = hv;
      hseq[((size_t)(b*SS + t))*512 + d*256 + tid] = hv;
    }
    __syncthreads();
  }
}

// -------- tag logits: emit[row][t] = hseq[row] . W_tag[t] + b_tag[t] --------
__global__ void k_emit(const float* __restrict__ hseq, const float* __restrict__ Wtag,
                       const float* __restrict__ btag, float* __restrict__ emit){
  int id = blockIdx.x*256 + threadIdx.x;
  if (id >= BS*TT) return;
  int row = id / TT, tg = id - row*TT;
  const float4* hp = (const float4*)(hseq + (size_t)row*512);
  const float4* wp = (const float4*)(Wtag + (size_t)tg*512);
  float acc = btag[tg];
  #pragma unroll 8
  for (int k = 0; k < 128; ++k){
    float4 h = hp[k], w = wp[k];
    acc += h.x*w.x + h.y*w.y + h.z*w.z + h.w*w.w;
  }
  emit[id] = acc;
}

// -------- CRF NLL (forward algorithm + gold score), one wave per batch --------
__global__ void k_crf(const float* __restrict__ emit, const int* __restrict__ msk,
                      const int* __restrict__ lab, const float* __restrict__ trans,
                      float* __restrict__ nll){
  int b = blockIdx.x, tid = threadIdx.x;
  __shared__ float tr[361];
  __shared__ float al[19];
  for (int i = tid; i < 361; i += 64) tr[i] = trans[i];
  const float* eb = emit + (size_t)b*SS*TT;
  const int* mb = msk + b*SS;
  const int* lb = lab + b*SS;
  __syncthreads();
  // gold path score + length (parallel over t, wave reduce)
  float gp = 0.f; int ln = 0;
  for (int t = tid; t < SS; t += 64){
    int m = mb[t];
    ln += m;
    if (m){
      int l = lb[t];
      int p = t ? lb[t-1] : START_TAG;
      gp += tr[p*19 + l] + eb[t*19 + l];
    }
  }
  for (int off = 32; off; off >>= 1){ gp += __shfl_down(gp, off); ln += __shfl_down(ln, off); }
  float gold = 0.f;
  if (tid == 0){
    int lt = lb[ln - 1];
    gold = gp + tr[lt*19 + STOP_TAG];
  }
  if (tid < 19) al[tid] = eb[tid] + tr[START_TAG*19 + tid];
  __syncthreads();
  for (int t = 1; t < SS; ++t){
    int m = mb[t];
    float nv = 0.f;
    if (tid < 19){
      float mx = -1e30f;
      for (int p = 0; p < 19; ++p){ float v = al[p] + tr[p*19 + tid]; mx = fmaxf(mx, v); }
      float sum = 0.f;
      for (int p = 0; p < 19; ++p) sum += expf(al[p] + tr[p*19 + tid] - mx);
      nv = mx + logf(sum) + eb[t*19 + tid];
    }
    __syncthreads();
    if (tid < 19 && m) al[tid] = nv;
    __syncthreads();
  }
  if (tid == 0){
    float mx = -1e30f;
    for (int c2 = 0; c2 < 19; ++c2) mx = fmaxf(mx, al[c2] + tr[c2*19 + STOP_TAG]);
    float sum = 0.f;
    for (int c2 = 0; c2 < 19; ++c2) sum += expf(al[c2] + tr[c2*19 + STOP_TAG] - mx);
    nll[b] = (mx + logf(sum)) - gold;
  }
}

// -------- Viterbi decode, one wave per batch; writes tags (as float) to d_out[1..] --------
__global__ void k_vit(const float* __restrict__ emit, const int* __restrict__ msk,
                      const float* __restrict__ trans, int* __restrict__ ptr,
                      float* __restrict__ out){
  int b = blockIdx.x, tid = threadIdx.x;
  __shared__ float tr[361];
  __shared__ float dl[19];
  __shared__ int tg[256];
  for (int i = tid; i < 361; i += 64) tr[i] = trans[i];
  const float* eb = emit + (size_t)b*SS*TT;
  const int* mb = msk + b*SS;
  int* pb = ptr + (size_t)b*SS*TT;
  if (tid < 19) dl[tid] = eb[tid] + tr[START_TAG*19 + tid];
  __syncthreads();
  for (int t = 1; t < SS; ++t){
    int m = mb[t];
    float best = -1e30f; int bp = 0;
    if (tid < 19){
      for (int p = 0; p < 19; ++p){
        float v = dl[p] + tr[p*19 + tid];
        if (v > best){ best = v; bp = p; }       // strict > == first-max (jnp.argmax)
      }
    }
    __syncthreads();
    if (tid < 19){
      if (m){ dl[tid] = best + eb[t*19 + tid]; pb[t*19 + tid] = bp; }
      else  { pb[t*19 + tid] = tid; }            // identity pass-through when padded
    }
    __syncthreads();
  }
  if (tid == 0){
    float bv = -1e30f; int bl = 0;
    for (int c2 = 0; c2 < 19; ++c2){
      float v = dl[c2] + tr[c2*19 + STOP_TAG];
      if (v > bv){ bv = v; bl = c2; }
    }
    tg[SS-1] = bl;
    for (int t = SS-1; t > 0; --t) tg[t-1] = pb[t*19 + tg[t]];
  }
  __syncthreads();
  for (int t = tid; t < SS; t += 64)
    out[1 + b*SS + t] = (float)(tg[t] * mb[t]);
}

// -------- final loss reduce: d_out[0] = sum(nll)/B --------
__global__ void k_final(const float* __restrict__ nll, float* __restrict__ out){
  int tid = threadIdx.x;
  float v = (tid < 32) ? nll[tid] : 0.f;
  for (int off = 32; off; off >>= 1) v += __shfl_down(v, off);
  if (tid == 0) out[0] = v * (1.0f/32.0f);
}

extern "C" void kernel_launch(void* const* d_in, const int* in_sizes, int n_in,
                              void* d_out, int out_size, void* d_ws, size_t ws_size,
                              hipStream_t stream){
  const int*   wi    = (const int*)d_in[0];
  const int*   msk   = (const int*)d_in[1];
  const int*   lab   = (const int*)d_in[2];
  // d_in[3] labels_token, d_in[4] data_type: unused (data_type==1 branch)
  const float* emb   = (const float*)d_in[5];
  const float* Wih_f = (const float*)d_in[6];
  const float* Whh_f = (const float*)d_in[7];
  const float* bih_f = (const float*)d_in[8];
  const float* bhh_f = (const float*)d_in[9];
  const float* Wih_b = (const float*)d_in[10];
  const float* Whh_b = (const float*)d_in[11];
  const float* bih_b = (const float*)d_in[12];
  const float* bhh_b = (const float*)d_in[13];
  const float* Wtag  = (const float*)d_in[14];
  const float* btag  = (const float*)d_in[15];
  const float* trans = (const float*)d_in[16];

  float* ws   = (float*)d_ws;
  float* x    = ws;
  float* WT   = ws + 2490368;
  float* bias = ws + 3112960;
  float4* Wp  = (float4*)(ws + 3115008);
  float* gin  = ws + 3639296;
  float* hseq = ws + 20416512;
  float* emit = ws + 24610816;
  int*   ptr  = (int*)(ws + 24766464);
  float* nll  = ws + 24922112;
  float* out  = (float*)d_out;

  hipLaunchKernelGGL(k_embed,    dim3(2432),    dim3(256),  0, stream, wi, msk, emb, x);
  hipLaunchKernelGGL(k_prep_wt,  dim3(2440),    dim3(256),  0, stream,
                     Wih_f, Wih_b, bih_f, bhh_f, bih_b, bhh_b, WT, bias);
  hipLaunchKernelGGL(k_prep_whh, dim3(256,2),   dim3(256),  0, stream, Whh_f, Whh_b, Wp);
  hipLaunchKernelGGL(k_gemm,     dim3(32,128),  dim3(256),  0, stream, x, WT, bias, gin);
  hipLaunchKernelGGL(k_lstm,     dim3(64),      dim3(1024), 0, stream, gin, Wp, hseq);
  hipLaunchKernelGGL(k_emit,     dim3(608),     dim3(256),  0, stream, hseq, Wtag, btag, emit);
  hipLaunchKernelGGL(k_crf,      dim3(32),      dim3(64),   0, stream, emit, msk, lab, trans, nll);
  hipLaunchKernelGGL(k_vit,      dim3(32),      dim3(64),   0, stream, emit, msk, trans, ptr, out);
  hipLaunchKernelGGL(k_final,    dim3(1),       dim3(64),   0, stream, nll, out);
}